// Round 1
// baseline (10044.334 us; speedup 1.0000x reference)
//
#include <hip/hip_runtime.h>
#include <stdint.h>
#include <math.h>

// ---------------------------------------------------------------------------
// Graph-generator RNN (B=512, H=256, 50 node steps, edge window 12).
// Deterministic recurrence: f32 tiled GEMM kernels (no fp32 MFMA on CDNA4).
// Stochastic path: exact JAX threefry2x32 ("partitionable" random-bits path),
// gumbel-softmax at temp=1e-3 fused into classifier kernels.
// ---------------------------------------------------------------------------

#define HDIM 256
#define BATCH 512
#define NSTEPS 50

// workspace layout (floats)
#define WS_EMB   0u            // 2 * 131072 (ring of node_embs)
#define WS_EGI   262144u       // 13 * 393216 (edge input-gate ring)
#define WS_NGI   5373952u      // 393216 (node input gates)
#define WS_H0    5767168u      // 131072 (latent projection)
#define WS_EHF   5898240u      // 2 * 131072 (edge_h final ping-pong)
#define WS_EOUT  6160384u      // 12 * 131072 (edge scan outputs)
#define WS_NN    7733248u      // 512 (num_nodes)
// total 7,733,760 floats = 30.9 MB

// output layout (floats)
#define O_NF 512u              // node feats [512][50][51]
#define O_EF 1306112u          // edge feats [522][512][9]
#define O_NL 3711488u          // node logprobs [512][50][3]
#define O_EL 3788288u          // edge logprobs [522][512][2]

// ---------------- threefry2x32 (exact JAX semantics) ----------------
__host__ __device__ inline void tf2x32(uint32_t k0, uint32_t k1,
                                       uint32_t x0, uint32_t x1,
                                       uint32_t& o0, uint32_t& o1) {
  uint32_t ks2 = k0 ^ k1 ^ 0x1BD11BDAu;
#define TFR(r) { x0 += x1; x1 = (x1 << r) | (x1 >> (32 - r)); x1 ^= x0; }
  x0 += k0; x1 += k1;
  TFR(13) TFR(15) TFR(26) TFR(6)
  x0 += k1; x1 += ks2 + 1u;
  TFR(17) TFR(29) TFR(16) TFR(24)
  x0 += ks2; x1 += k0 + 2u;
  TFR(13) TFR(15) TFR(26) TFR(6)
  x0 += k0; x1 += k1 + 3u;
  TFR(17) TFR(29) TFR(16) TFR(24)
  x0 += k1; x1 += ks2 + 4u;
  TFR(13) TFR(15) TFR(26) TFR(6)
  x0 += ks2; x1 += k0 + 5u;
#undef TFR
  o0 = x0; o1 = x1;
}

// JAX >=0.4.36 default: jax_threefry_partitionable=True.
// bits[i] = o0 ^ o1 with counter (hi32(i)=0, lo32(i)=i).
// (Fallback if wrong: original path pairs (i, i+size/2), word chosen by half.)
__device__ inline float gumbel_at(uint32_t k0, uint32_t k1, uint32_t idx) {
  uint32_t o0, o1;
  tf2x32(k0, k1, 0u, idx, o0, o1);
  uint32_t bits = o0 ^ o1;
  float u = __uint_as_float((bits >> 9) | 0x3f800000u) - 1.0f;
  u = fmaxf(u, 1.1754943508222875e-38f);   // minval = finfo(f32).tiny
  return -logf(-logf(u));
}

// ---------------- init / final ----------------
__global__ void init_k(float* __restrict__ ehf0, float* __restrict__ nn) {
  int i = blockIdx.x * 256 + threadIdx.x;   // grid 512x256 = 131072
  ehf0[i] = 0.f;
  if (i < 512) nn[i] = -1.f;
}

__global__ void final_k(const float* __restrict__ nn, float* __restrict__ out) {
  int b = threadIdx.x;                      // 512 threads
  float v = nn[b];
  out[b] = (v == -1.f) ? 50.f : v;
}

// ---------------- latent projection + SELU ----------------
__global__ __launch_bounds__(256)
void latproj(const float* __restrict__ z, const float* __restrict__ W,
             const float* __restrict__ bias, float* __restrict__ out) {
  int m = blockIdx.x;     // 512
  int j = threadIdx.x;    // 256
  __shared__ float zs[128];
  if (j < 128) zs[j] = z[m * 128 + j];
  __syncthreads();
  float s = 0.f;
  for (int k = 0; k < 128; ++k) s += zs[k] * W[j * 128 + k];
  s += bias[j];
  const float alpha = 1.6732632423543772f, scale = 1.0507009873554805f;
  out[m * HDIM + j] = scale * (s > 0.f ? s : alpha * expm1f(s));
}

// ---------------- fused GRU GEMM ----------------
// MODE_GI (gi==nullptr): out[512][768] = A@W.T + bias      (A may be nullptr -> 0)
// MODE_STEP (gi!=nullptr): gh = (A+A2)@W.T + bias; GRU-combine with gi, h=(A+A2)
//                          out[512][256] (+ optional copy out2)
__global__ __launch_bounds__(256)
void gru_gemm(const float* __restrict__ A, const float* __restrict__ A2,
              const float* __restrict__ W, const float* __restrict__ bias,
              const float* __restrict__ gi, float* __restrict__ out,
              float* __restrict__ out2) {
  __shared__ float As[32][68];
  __shared__ float Ws[48][68];
  const int t  = threadIdx.x;
  const int m0 = blockIdx.x * 32;   // gridDim.x = 16
  const int j0 = blockIdx.y * 16;   // gridDim.y = 16
  const int jj = t & 15;
  const int mr = (t >> 4) * 2;
  float a00 = 0.f, a01 = 0.f, a02 = 0.f, a10 = 0.f, a11 = 0.f, a12 = 0.f;
  if (A) {
    for (int k0 = 0; k0 < HDIM; k0 += 64) {
#pragma unroll
      for (int r = 0; r < 2; ++r) {            // stage A (32x64)
        int idx = t + r * 256;
        int row = idx >> 4;
        int c = (idx & 15) << 2;
        float4 v = *(const float4*)(A + (size_t)(m0 + row) * HDIM + k0 + c);
        if (A2) {
          float4 v2 = *(const float4*)(A2 + (size_t)(m0 + row) * HDIM + k0 + c);
          v.x += v2.x; v.y += v2.y; v.z += v2.z; v.w += v2.w;
        }
        *(float4*)&As[row][c] = v;
      }
#pragma unroll
      for (int r = 0; r < 3; ++r) {            // stage W (48x64), rows g*256+j0+jl
        int idx = t + r * 256;
        int row = idx >> 4;
        int c = (idx & 15) << 2;
        int g = row >> 4, jl = row & 15;
        *(float4*)&Ws[row][c] =
            *(const float4*)(W + (size_t)(g * 256 + j0 + jl) * HDIM + k0 + c);
      }
      __syncthreads();
#pragma unroll
      for (int kk = 0; kk < 64; kk += 4) {
        float4 x0 = *(const float4*)&As[mr][kk];
        float4 x1 = *(const float4*)&As[mr + 1][kk];
        float4 w0 = *(const float4*)&Ws[jj][kk];
        float4 w1 = *(const float4*)&Ws[16 + jj][kk];
        float4 w2 = *(const float4*)&Ws[32 + jj][kk];
        a00 += x0.x * w0.x + x0.y * w0.y + x0.z * w0.z + x0.w * w0.w;
        a01 += x0.x * w1.x + x0.y * w1.y + x0.z * w1.z + x0.w * w1.w;
        a02 += x0.x * w2.x + x0.y * w2.y + x0.z * w2.z + x0.w * w2.w;
        a10 += x1.x * w0.x + x1.y * w0.y + x1.z * w0.z + x1.w * w0.w;
        a11 += x1.x * w1.x + x1.y * w1.y + x1.z * w1.z + x1.w * w1.w;
        a12 += x1.x * w2.x + x1.y * w2.y + x1.z * w2.z + x1.w * w2.w;
      }
      __syncthreads();
    }
  }
  const int col = j0 + jj;
#pragma unroll
  for (int ml = 0; ml < 2; ++ml) {
    int m = m0 + mr + ml;
    float g0 = ml ? a10 : a00;
    float g1 = ml ? a11 : a01;
    float g2 = ml ? a12 : a02;
    if (!gi) {
      out[(size_t)m * 768 + col]       = g0 + bias[col];
      out[(size_t)m * 768 + 256 + col] = g1 + bias[256 + col];
      out[(size_t)m * 768 + 512 + col] = g2 + bias[512 + col];
    } else {
      float hr = g0 + bias[col];
      float hz = g1 + bias[256 + col];
      float hn = g2 + bias[512 + col];
      float ir  = gi[(size_t)m * 768 + col];
      float iz  = gi[(size_t)m * 768 + 256 + col];
      float inn = gi[(size_t)m * 768 + 512 + col];
      float h = A[(size_t)m * HDIM + col] + (A2 ? A2[(size_t)m * HDIM + col] : 0.f);
      float r  = 1.f / (1.f + expf(-(ir + hr)));
      float zg = 1.f / (1.f + expf(-(iz + hz)));
      float n  = tanhf(inn + r * hn);
      float hv = (1.f - zg) * n + zg * h;
      out[(size_t)m * HDIM + col] = hv;
      if (out2) out2[(size_t)m * HDIM + col] = hv;
    }
  }
}

// ---------------- node classifiers + gumbel sampling ----------------
__global__ __launch_bounds__(64)
void node_cls(const float* __restrict__ emb,
              const float* __restrict__ W0, const float* __restrict__ b0,
              const float* __restrict__ W1, const float* __restrict__ b1,
              const float* __restrict__ W2, const float* __restrict__ b2,
              float* __restrict__ out_feats, float* __restrict__ out_lp,
              float* __restrict__ num_nodes, int step,
              uint32_t ka0, uint32_t ka1, uint32_t kb0, uint32_t kb1,
              uint32_t kc0, uint32_t kc1) {
  const int b = blockIdx.x;
  const int lane = threadIdx.x;
  const float e0 = emb[(size_t)b * HDIM + lane];
  const float e1 = emb[(size_t)b * HDIM + lane + 64];
  const float e2 = emb[(size_t)b * HDIM + lane + 128];
  const float e3 = emb[(size_t)b * HDIM + lane + 192];

  auto phase = [&](const float* W, const float* bb, int nf, uint32_t kk0,
                   uint32_t kk1, int coff, int jidx, bool do_arg) {
    float ml = 0.f;
    for (int jf = 0; jf < nf; ++jf) {
      const float* wr = W + (size_t)jf * HDIM;
      float p = e0 * wr[lane] + e1 * wr[lane + 64] + e2 * wr[lane + 128] +
                e3 * wr[lane + 192];
#pragma unroll
      for (int d = 32; d; d >>= 1) p += __shfl_xor(p, d);
      if (lane == jf) ml = p + bb[jf];
    }
    const bool act = lane < nf;
    float g = act ? gumbel_at(kk0, kk1, (uint32_t)(b * nf + lane)) : 0.f;
    float tv = act ? (ml + g) / 1e-3f : -INFINITY;
    float mx = tv;
#pragma unroll
    for (int d = 32; d; d >>= 1) mx = fmaxf(mx, __shfl_xor(mx, d));
    float e = act ? expf(tv - mx) : 0.f;
    float se = e;
#pragma unroll
    for (int d = 32; d; d >>= 1) se += __shfl_xor(se, d);
    float s = act ? e / se : 0.f;
    // log_softmax of logits (node path)
    float lv = act ? ml : -INFINITY;
    float mx2 = lv;
#pragma unroll
    for (int d = 32; d; d >>= 1) mx2 = fmaxf(mx2, __shfl_xor(mx2, d));
    float e2v = act ? expf(ml - mx2) : 0.f;
    float se2 = e2v;
#pragma unroll
    for (int d = 32; d; d >>= 1) se2 += __shfl_xor(se2, d);
    float logp = ml - mx2 - logf(se2);
    float w = act ? s * logp : 0.f;
#pragma unroll
    for (int d = 32; d; d >>= 1) w += __shfl_xor(w, d);
    if (act) out_feats[((size_t)b * 50 + step) * 51 + coff + lane] = s;
    if (lane == 0) out_lp[((size_t)b * 50 + step) * 3 + jidx] = w;
    if (do_arg) {
      float av = act ? s : -1.f;
      int ai = lane;
#pragma unroll
      for (int d = 32; d; d >>= 1) {
        float ov = __shfl_xor(av, d);
        int oi = __shfl_xor(ai, d);
        if (ov > av || (ov == av && oi < ai)) { av = ov; ai = oi; }
      }
      if (lane == 0 && ai == 39 && num_nodes[b] == -1.0f)
        num_nodes[b] = (float)(step + 1);
    }
  };
  phase(W0, b0, 40, ka0, ka1, 0, 0, true);
  phase(W1, b1, 6, kb0, kb1, 40, 1, false);
  phase(W2, b2, 5, kc0, kc1, 46, 2, false);
}

// ---------------- edge classifiers + gumbel sampling ----------------
__global__ __launch_bounds__(64)
void edge_cls(const float* __restrict__ eout,
              const float* __restrict__ W0, const float* __restrict__ b0,
              const float* __restrict__ W1, const float* __restrict__ b1,
              float* __restrict__ out_ef, float* __restrict__ out_elp,
              int L, int base,
              uint32_t ka0, uint32_t ka1, uint32_t kb0, uint32_t kb1) {
  const int r = blockIdx.x;          // 0..L*512-1 (row of reversed edge_out)
  const int tt = r >> 9, b = r & 511;
  const int lane = threadIdx.x;
  const float* row = eout + ((size_t)(L - 1 - tt) * 512 + b) * HDIM;
  const float e0 = row[lane];
  const float e1 = row[lane + 64];
  const float e2 = row[lane + 128];
  const float e3 = row[lane + 192];
  const size_t orow = (size_t)(base + tt) * 512 + b;

  auto phase = [&](const float* W, const float* bb, int nf, uint32_t kk0,
                   uint32_t kk1, int coff, int jidx) {
    float ml = 0.f;
    for (int jf = 0; jf < nf; ++jf) {
      const float* wr = W + (size_t)jf * HDIM;
      float p = e0 * wr[lane] + e1 * wr[lane + 64] + e2 * wr[lane + 128] +
                e3 * wr[lane + 192];
#pragma unroll
      for (int d = 32; d; d >>= 1) p += __shfl_xor(p, d);
      if (lane == jf) ml = p + bb[jf];
    }
    const bool act = lane < nf;
    float g = act ? gumbel_at(kk0, kk1, (uint32_t)(r * nf + lane)) : 0.f;
    float tv = act ? (ml + g) / 1e-3f : -INFINITY;
    float mx = tv;
#pragma unroll
    for (int d = 32; d; d >>= 1) mx = fmaxf(mx, __shfl_xor(mx, d));
    float e = act ? expf(tv - mx) : 0.f;
    float se = e;
#pragma unroll
    for (int d = 32; d; d >>= 1) se += __shfl_xor(se, d);
    float s = act ? e / se : 0.f;
    // NOTE: edge path takes log_softmax of the SAMPLES (faithful to source)
    float sv = act ? s : -INFINITY;
    float mx2 = sv;
#pragma unroll
    for (int d = 32; d; d >>= 1) mx2 = fmaxf(mx2, __shfl_xor(mx2, d));
    float e2v = act ? expf(s - mx2) : 0.f;
    float se2 = e2v;
#pragma unroll
    for (int d = 32; d; d >>= 1) se2 += __shfl_xor(se2, d);
    float logp = s - mx2 - logf(se2);
    float w = act ? s * logp : 0.f;
#pragma unroll
    for (int d = 32; d; d >>= 1) w += __shfl_xor(w, d);
    if (act) out_ef[orow * 9 + coff + lane] = s;
    if (lane == 0) out_elp[orow * 2 + jidx] = w;
  };
  phase(W0, b0, 5, ka0, ka1, 0, 0);
  phase(W1, b1, 4, kb0, kb1, 5, 1);
}

// ---------------- host ----------------
static inline void host_fold(uint32_t d, uint32_t& k0, uint32_t& k1) {
  tf2x32(0u, 42u, 0u, d, k0, k1);   // fold_in(key(42), d)
}

extern "C" void kernel_launch(void* const* d_in, const int* in_sizes, int n_in,
                              void* d_out, int out_size, void* d_ws,
                              size_t ws_size, hipStream_t stream) {
  (void)in_sizes; (void)n_in; (void)out_size; (void)ws_size;
  const float* z    = (const float*)d_in[0];
  const float* lpW  = (const float*)d_in[1];
  const float* lpb  = (const float*)d_in[2];
  const float* nWih = (const float*)d_in[3];
  const float* nWhh = (const float*)d_in[4];
  const float* nbih = (const float*)d_in[5];
  const float* nbhh = (const float*)d_in[6];
  const float* eWih = (const float*)d_in[7];
  const float* eWhh = (const float*)d_in[8];
  const float* ebih = (const float*)d_in[9];
  const float* ebhh = (const float*)d_in[10];
  const float* ncW0 = (const float*)d_in[11];
  const float* ncb0 = (const float*)d_in[12];
  const float* ncW1 = (const float*)d_in[13];
  const float* ncb1 = (const float*)d_in[14];
  const float* ncW2 = (const float*)d_in[15];
  const float* ncb2 = (const float*)d_in[16];
  const float* ecW0 = (const float*)d_in[17];
  const float* ecb0 = (const float*)d_in[18];
  const float* ecW1 = (const float*)d_in[19];
  const float* ecb1 = (const float*)d_in[20];

  float* ws    = (float*)d_ws;
  float* embs  = ws + WS_EMB;
  float* egi   = ws + WS_EGI;
  float* ngi   = ws + WS_NGI;
  float* h0b   = ws + WS_H0;
  float* ehf   = ws + WS_EHF;
  float* eoutb = ws + WS_EOUT;
  float* nn    = ws + WS_NN;

  float* out  = (float*)d_out;
  float* o_nf = out + O_NF;
  float* o_ef = out + O_EF;
  float* o_nl = out + O_NL;
  float* o_el = out + O_EL;

  init_k<<<dim3(512), dim3(256), 0, stream>>>(ehf, nn);
  latproj<<<dim3(512), dim3(256), 0, stream>>>(z, lpW, lpb, h0b);

  dim3 gg(16, 16), gb(256);
  int ep = 0, base = 0;
  for (int i = 0; i < NSTEPS; ++i) {
    float* embi = embs + (size_t)(i & 1) * 131072;
    const float* xprev = i ? embs + (size_t)((i - 1) & 1) * 131072 : nullptr;
    // node input gates: gi = x @ nWih.T + nbih   (x=0 at i=0)
    gru_gemm<<<gg, gb, 0, stream>>>(xprev, nullptr, nWih, nbih, nullptr, ngi,
                                    nullptr);
    // node GRU step: h_in = emb[i-1] (+ edge_h final for i>=2), h0 at i=0
    const float* hin = i ? xprev : h0b;
    const float* hadd = (i >= 2) ? ehf + (size_t)ep * 131072 : nullptr;
    gru_gemm<<<gg, gb, 0, stream>>>(hin, hadd, nWhh, nbhh, ngi, embi, nullptr);
    // node classifiers + sampling + num_nodes
    uint32_t ka0, ka1, kb0, kb1, kc0, kc1;
    host_fold((uint32_t)(i * 100 + 0), ka0, ka1);
    host_fold((uint32_t)(i * 100 + 1), kb0, kb1);
    host_fold((uint32_t)(i * 100 + 2), kc0, kc1);
    node_cls<<<dim3(512), dim3(64), 0, stream>>>(
        embi, ncW0, ncb0, ncW1, ncb1, ncW2, ncb2, o_nf, o_nl, nn, i, ka0, ka1,
        kb0, kb1, kc0, kc1);
    // edge input gates for emb i (used by steps i+1..i+12)
    if (i <= 48)
      gru_gemm<<<gg, gb, 0, stream>>>(embi, nullptr, eWih, ebih, nullptr,
                                      egi + (size_t)(i % 13) * 393216, nullptr);
    if (i >= 1) {
      int L = i < 12 ? i : 12;
      for (int tt = 0; tt < L; ++tt) {
        const float* hh0 = tt == 0 ? ehf + (size_t)ep * 131072
                                   : eoutb + (size_t)(tt - 1) * 131072;
        const float* hh1 = tt == 0 ? embi : nullptr;   // edge_h += node_h
        float* oh = eoutb + (size_t)tt * 131072;
        float* o2 = (tt == L - 1) ? ehf + (size_t)(1 - ep) * 131072 : nullptr;
        gru_gemm<<<gg, gb, 0, stream>>>(
            hh0, hh1, eWhh, ebhh, egi + (size_t)((i - 1 - tt) % 13) * 393216,
            oh, o2);
      }
      ep = 1 - ep;
      uint32_t ea0, ea1, eb0, eb1;
      host_fold((uint32_t)(i * 100 + 50 + 0), ea0, ea1);
      host_fold((uint32_t)(i * 100 + 50 + 1), eb0, eb1);
      edge_cls<<<dim3(L * 512), dim3(64), 0, stream>>>(
          eoutb, ecW0, ecb0, ecW1, ecb1, o_ef, o_el, L, base, ea0, ea1, eb0,
          eb1);
      base += L;
    }
  }
  final_k<<<dim3(1), dim3(512), 0, stream>>>(nn, out);
}